// Round 1
// 1687.439 us; speedup vs baseline: 1.2277x; 1.2277x over previous
//
#include <hip/hip_runtime.h>

#define BB   16
#define NNN  4000
#define DD   128
#define HH   4
#define KK   32
#define HK   128

// ---- workspace layout ----
// double region (dws = (double*)ws):
#define DOFF_MD    0        // [B][D] mean-sums (atomic double)   2048 d
#define DOFF_CENTD 2048     // cent [B][HK][D] double             262144 d
#define DOFF_CENTN 264192   // cent norms [B][HK] double          2048 d
#define DOFF_NODEN 266240   // node norms [B][N] double           64000 d
// float region (ws = (float*)ws), offsets in floats:
#define FOFF_CKD    660480  // Cn [B][K][D] (atomic)              65536 f
#define FOFF_ADJACC 726016  // adj accumulator [B][K][K] (atomic) 16384 f
#define FOFF_CMAT   742400  // C [B][N][K]                        2048000 f
#define FOFF_T      2790400 // T [B][K][N] (atomic now)           2048000 f
// total 4838400 floats = 19.35 MB

// zero: MD (4096 f) + CKD+ADJACC (81920 f) + T (2048000 f) = 2134016 f = 8336*256
__global__ void k_zero(float* __restrict__ ws){
  int i = blockIdx.x * 256 + threadIdx.x;
  if (i < 4096) ws[i] = 0.f;
  else if (i < 4096 + 81920) ws[FOFF_CKD + (i - 4096)] = 0.f;
  else ws[FOFF_T + (i - (4096 + 81920))] = 0.f;
}

// column sums of node over n -> atomicAdd(double)
// 640 blocks (16 b x 40 chunks of 100 rows), 4 independent chains for MLP depth
__global__ __launch_bounds__(128) void k_mean(const float* __restrict__ node, double* __restrict__ dws){
  int b = blockIdx.x / 40, c = blockIdx.x % 40, d = threadIdx.x;
  const float* p = node + ((size_t)(b * NNN + c * 100)) * DD + d;
  double s0 = 0.0, s1 = 0.0, s2 = 0.0, s3 = 0.0;
  for (int n = 0; n < 100; n += 4){
    s0 += (double)p[(size_t)(n + 0) * DD];
    s1 += (double)p[(size_t)(n + 1) * DD];
    s2 += (double)p[(size_t)(n + 2) * DD];
    s3 += (double)p[(size_t)(n + 3) * DD];
  }
  atomicAdd(&dws[DOFF_MD + b * DD + d], (s0 + s1) + (s2 + s3));
}

__global__ __launch_bounds__(64) void k_norm_node(const float* __restrict__ src, double* __restrict__ dst){
  int row = blockIdx.x, lane = threadIdx.x;
  float2 v = reinterpret_cast<const float2*>(src + (size_t)row * DD)[lane];
  double s = (double)v.x * (double)v.x + (double)v.y * (double)v.y;
  #pragma unroll
  for (int o = 32; o; o >>= 1) s += __shfl_down(s, o);
  if (lane == 0) dst[row] = sqrt(s);
}

__global__ __launch_bounds__(64) void k_norm_cent(const double* __restrict__ src, double* __restrict__ dst){
  int row = blockIdx.x, lane = threadIdx.x;
  double2 v = reinterpret_cast<const double2*>(src + (size_t)row * DD)[lane];
  double s = v.x * v.x + v.y * v.y;
  #pragma unroll
  for (int o = 32; o; o >>= 1) s += __shfl_down(s, o);
  if (lane == 0) dst[row] = sqrt(s);
}

// centroid MLP in double: m -> 16 -> 64 -> 128, store centD[b][hk][d]
__global__ __launch_bounds__(128) void k_mlp(const float* __restrict__ w1, const float* __restrict__ b1,
                                             const float* __restrict__ W2, const float* __restrict__ b2,
                                             const float* __restrict__ W3, const float* __restrict__ b3,
                                             double* __restrict__ dws){
  int b = blockIdx.x, d = threadIdx.x;
  double mv = dws[DOFF_MD + b * DD + d] * (1.0 / NNN);
  double c1[16];
  #pragma unroll
  for (int j = 0; j < 16; ++j) c1[j] = fmax(mv * (double)w1[j] + (double)b1[j], 0.0);
  double c2[64];
  for (int j = 0; j < 64; ++j){
    double s = (double)b2[j];
    #pragma unroll
    for (int i = 0; i < 16; ++i) s += (double)W2[j * 16 + i] * c1[i];
    c2[j] = fmax(s, 0.0);
  }
  for (int j = 0; j < HK; ++j){
    double s = (double)b3[j];
    #pragma unroll
    for (int i = 0; i < 64; ++i) s += (double)W3[j * 64 + i] * c2[i];
    dws[DOFF_CENTD + ((size_t)b * HK + j) * DD + d] = fmax(s, 0.0);
  }
}

// dots (fp64) + cosine + K-normalization + head mix -> C [b][n][k] (fp32)
__global__ __launch_bounds__(256) void k_dots(const float* __restrict__ node,
                                              const float* __restrict__ convw,
                                              const float* __restrict__ convb,
                                              float* __restrict__ ws,
                                              const double* __restrict__ dws){
  __shared__ double centL[16 * 132];   // 16.9 KB
  __shared__ float  nodePart[8448];    // nodeL [64][129]=8256, reused as part[256][33]
  float* nodeL = nodePart;
  float* part  = nodePart;
  int t = threadIdx.x;
  int b = blockIdx.x / 63, tile = blockIdx.x % 63;
  int n0 = tile * 64;
  int nl = t & 63, h = t >> 6;

  for (int i = t; i < 64 * DD; i += 256){
    int n = i >> 7, d = i & 127;
    float v = (n0 + n < NNN) ? node[((size_t)b * NNN + n0 + n) * DD + d] : 0.f;
    nodeL[n * 129 + d] = v;
  }
  double acc[32];
  #pragma unroll
  for (int k = 0; k < 32; ++k) acc[k] = 0.0;
  const double* centg = dws + DOFF_CENTD + (size_t)b * HK * DD;
  for (int dc = 0; dc < 8; ++dc){
    __syncthreads();
    for (int i = t; i < 2048; i += 256){
      int hk = i >> 4, dd = i & 15;
      centL[dd * 132 + hk] = centg[(size_t)hk * DD + dc * 16 + dd];
    }
    __syncthreads();
    for (int dd = 0; dd < 16; ++dd){
      double nv = (double)nodeL[nl * 129 + dc * 16 + dd];
      const double* c = centL + dd * 132 + h * 32;
      #pragma unroll
      for (int k = 0; k < 32; ++k) acc[k] += c[k] * nv;
    }
  }
  int gn = n0 + nl;
  float contrib[32];
  {
    double nnv = (gn < NNN) ? dws[DOFF_NODEN + b * NNN + gn] : 1.0;
    const double* cnp = dws + DOFF_CENTN + b * HK + h * KK;
    double cs[32], S = 0.0;
    #pragma unroll
    for (int k = 0; k < 32; ++k){
      cs[k] = acc[k] / fmax(cnp[k] * nnv, 1e-6);
      S += cs[k];
    }
    double wh = (double)convw[h] / (S + 1e-10);
    #pragma unroll
    for (int k = 0; k < 32; ++k) contrib[k] = (float)(cs[k] * wh);
  }
  __syncthreads();
  #pragma unroll
  for (int k = 0; k < 32; ++k) part[(h * 64 + nl) * 33 + k] = contrib[k];
  __syncthreads();
  float cb = convb[0];
  for (int i = t; i < 64 * 32; i += 256){
    int n = i >> 5, k = i & 31;
    if (n0 + n < NNN){
      float v = cb + part[n * 33 + k] + part[(64 + n) * 33 + k]
                   + part[(128 + n) * 33 + k] + part[(192 + n) * 33 + k];
      ws[FOFF_CMAT + ((size_t)b * NNN + n0 + n) * KK + k] = v;
    }
  }
}

// T[b][k][m] += sum_{n in split} C[b][n][k] * adj[b][n][m]
// grid 2048 = 16 b x 16 m-tiles x 8 n-splits -> 8 blocks/CU = 32 waves/CU.
// n-splits of 512 (last 416) keep staged chunks multiples of 16.
// Partial sums combined via atomicAdd into zeroed T.
__global__ __launch_bounds__(256) void k_cadj(const float* __restrict__ adj, float* __restrict__ ws){
  __shared__ float CL[128 * 32];
  int t = threadIdx.x;
  int b   = blockIdx.x >> 7;
  int mt  = (blockIdx.x >> 3) & 15;
  int nsp = blockIdx.x & 7;
  int m = mt * 256 + t;
  int mload = m < NNN ? m : NNN - 1;
  const float* adjp = adj + (size_t)b * NNN * NNN + mload;
  const float* Cg = ws + FOFF_CMAT + (size_t)b * NNN * KK;
  float acc[32];
  #pragma unroll
  for (int k = 0; k < 32; ++k) acc[k] = 0.f;
  int nstart = nsp * 512;
  int nend = nstart + 512; if (nend > NNN) nend = NNN;
  for (int n0 = nstart; n0 < nend; n0 += 128){
    int cnt = min(128, nend - n0);
    __syncthreads();
    const float4* src4 = reinterpret_cast<const float4*>(Cg + (size_t)n0 * KK);
    float4* dst4 = reinterpret_cast<float4*>(CL);
    for (int i = t; i < cnt * 8; i += 256) dst4[i] = src4[i];
    __syncthreads();
    for (int g = 0; g < cnt; g += 16){
      float av[16];
      #pragma unroll
      for (int u = 0; u < 16; ++u) av[u] = adjp[(size_t)(n0 + g + u) * NNN];
      #pragma unroll
      for (int u = 0; u < 16; ++u){
        const float4* c4 = reinterpret_cast<const float4*>(CL + (g + u) * 32);
        #pragma unroll
        for (int k4 = 0; k4 < 8; ++k4){
          float4 cv = c4[k4];
          acc[k4 * 4 + 0] += cv.x * av[u]; acc[k4 * 4 + 1] += cv.y * av[u];
          acc[k4 * 4 + 2] += cv.z * av[u]; acc[k4 * 4 + 3] += cv.w * av[u];
        }
      }
    }
  }
  if (m < NNN){
    float* Tg = ws + FOFF_T + (size_t)b * KK * NNN + m;
    #pragma unroll
    for (int k = 0; k < 32; ++k) atomicAdd(&Tg[(size_t)k * NNN], acc[k]);
  }
}

// Cn[b][k][d] += sum_{n in chunk} C[b][n][k] * node[b][n][d]
__global__ __launch_bounds__(128) void k_cnode(const float* __restrict__ node, float* __restrict__ ws){
  __shared__ float CL[125 * 32];
  int t = threadIdx.x;
  int b = blockIdx.x >> 5, c = blockIdx.x & 31;
  int nbase = c * 125;
  const float* Cg = ws + FOFF_CMAT + ((size_t)b * NNN + nbase) * KK;
  const float* np = node + ((size_t)b * NNN + nbase) * DD + t;
  const float4* src4 = reinterpret_cast<const float4*>(Cg);
  float4* dst4 = reinterpret_cast<float4*>(CL);
  for (int i = t; i < 1000; i += 128) dst4[i] = src4[i];
  float acc[32];
  #pragma unroll
  for (int k = 0; k < 32; ++k) acc[k] = 0.f;
  __syncthreads();
  #pragma unroll 5
  for (int r = 0; r < 125; ++r){
    float nv = np[(size_t)r * DD];
    const float4* c4 = reinterpret_cast<const float4*>(CL + r * 32);
    #pragma unroll
    for (int k4 = 0; k4 < 8; ++k4){
      float4 cv = c4[k4];
      acc[k4 * 4 + 0] += cv.x * nv; acc[k4 * 4 + 1] += cv.y * nv;
      acc[k4 * 4 + 2] += cv.z * nv; acc[k4 * 4 + 3] += cv.w * nv;
    }
  }
  float* Cn = ws + FOFF_CKD + (size_t)b * KK * DD + t;
  #pragma unroll
  for (int k = 0; k < 32; ++k) atomicAdd(&Cn[k * DD], acc[k]);
}

// out1[b][k][o] = lin_b[o] + sum_d Cn[b][k][d]*lin_w[o][d]
__global__ __launch_bounds__(128) void k_newnode(const float* __restrict__ lw, const float* __restrict__ lb,
                                                 const float* __restrict__ ws, float* __restrict__ out){
  __shared__ float cnl[DD];
  int t = threadIdx.x;
  int b = blockIdx.x >> 5, k = blockIdx.x & 31;
  cnl[t] = ws[FOFF_CKD + ((size_t)b * KK + k) * DD + t];
  __syncthreads();
  float s = lb[t];
  const float4* w4 = reinterpret_cast<const float4*>(lw + t * DD);
  const float4* c4 = reinterpret_cast<const float4*>(cnl);
  #pragma unroll 8
  for (int d4 = 0; d4 < 32; ++d4){
    float4 w = w4[d4], c = c4[d4];
    s += w.x * c.x + w.y * c.y + w.z * c.z + w.w * c.w;
  }
  out[((size_t)b * KK + k) * DD + t] = s;
}

// partial new_adj: acc[k] = sum_m T[b][k][m]*C[b][m][j], atomicAdd into adjacc
// grid 256 = 16 b x 16 m-chunks of 250
__global__ __launch_bounds__(256) void k_newadjp(float* __restrict__ ws){
  __shared__ float red[32 * 33];
  int t = threadIdx.x;
  int b = blockIdx.x >> 4, mc = blockIdx.x & 15;
  int j = t & 31, ms = t >> 5;
  const float* Cg = ws + FOFF_CMAT + (size_t)b * NNN * KK;
  const float* Tg = ws + FOFF_T + (size_t)b * KK * NNN;
  float acc[32];
  #pragma unroll
  for (int k = 0; k < 32; ++k) acc[k] = 0.f;
  for (int l = ms; l < 250; l += 8){
    int m = mc * 250 + l;
    float cv = Cg[(size_t)m * KK + j];
    #pragma unroll
    for (int k = 0; k < 32; ++k) acc[k] += Tg[(size_t)k * NNN + m] * cv;
  }
  for (int g = 0; g < 8; ++g){
    if (ms == g){
      if (g == 0){
        #pragma unroll
        for (int k = 0; k < 32; ++k) red[k * 33 + j] = acc[k];
      } else {
        #pragma unroll
        for (int k = 0; k < 32; ++k) red[k * 33 + j] += acc[k];
      }
    }
    __syncthreads();
  }
  for (int i = t; i < 1024; i += 256){
    int k = i >> 5, j2 = i & 31;
    atomicAdd(&ws[FOFF_ADJACC + ((size_t)b * KK + k) * KK + j2], red[k * 33 + j2]);
  }
}

__global__ void k_adjfinal(const float* __restrict__ ws, float* __restrict__ out){
  int i = blockIdx.x * 256 + threadIdx.x;
  if (i < BB * KK * KK) out[i] = fmaxf(ws[FOFF_ADJACC + i], 0.f);
}

extern "C" void kernel_launch(void* const* d_in, const int* in_sizes, int n_in,
                              void* d_out, int out_size, void* d_ws, size_t ws_size,
                              hipStream_t stream){
  const float* node = (const float*)d_in[0];
  const float* adj  = (const float*)d_in[1];
  const float* w1   = (const float*)d_in[2];
  const float* b1   = (const float*)d_in[3];
  const float* W2   = (const float*)d_in[4];
  const float* b2   = (const float*)d_in[5];
  const float* W3   = (const float*)d_in[6];
  const float* b3   = (const float*)d_in[7];
  const float* cw   = (const float*)d_in[8];
  const float* cb   = (const float*)d_in[9];
  const float* lw   = (const float*)d_in[10];
  const float* lb   = (const float*)d_in[11];
  float* out  = (float*)d_out;
  float* ws   = (float*)d_ws;
  double* dws = (double*)d_ws;

  hipLaunchKernelGGL(k_zero,      dim3(8336),     dim3(256), 0, stream, ws);
  hipLaunchKernelGGL(k_mean,      dim3(640),      dim3(128), 0, stream, node, dws);
  hipLaunchKernelGGL(k_norm_node, dim3(BB * NNN), dim3(64),  0, stream, node, dws + DOFF_NODEN);
  hipLaunchKernelGGL(k_mlp,       dim3(16),       dim3(128), 0, stream, w1, b1, W2, b2, W3, b3, dws);
  hipLaunchKernelGGL(k_norm_cent, dim3(BB * HK),  dim3(64),  0, stream, dws + DOFF_CENTD, dws + DOFF_CENTN);
  hipLaunchKernelGGL(k_dots,      dim3(16 * 63),  dim3(256), 0, stream, node, cw, cb, ws, dws);
  hipLaunchKernelGGL(k_cadj,      dim3(2048),     dim3(256), 0, stream, adj, ws);
  hipLaunchKernelGGL(k_cnode,     dim3(512),      dim3(128), 0, stream, node, ws);
  hipLaunchKernelGGL(k_newnode,   dim3(512),      dim3(128), 0, stream, lw, lb, ws, out);
  hipLaunchKernelGGL(k_newadjp,   dim3(256),      dim3(256), 0, stream, ws);
  hipLaunchKernelGGL(k_adjfinal,  dim3(64),       dim3(256), 0, stream, ws, out + BB * KK * DD);
}